// Round 8
// baseline (64.681 us; speedup 1.0000x reference)
//
#include <hip/hip_runtime.h>
#include <stdint.h>

#define NB 8
#define NI 16
#define NC 256
#define SH 512
#define NCH 84   // 256-pixel chunks per batch: 64 (L0) + 16 (L1) + 4 (L2)

typedef __bf16 bf16x8 __attribute__((ext_vector_type(8)));
typedef float f32x4 __attribute__((ext_vector_type(4)));
typedef uint32_t u32x4 __attribute__((ext_vector_type(4)));

// ws layout (bytes) — every slot written unconditionally every call: NO memset.
static const size_t OFF_SSP = 0;                                         // f32 [NB][NCH][NI][NC]
static const size_t OFF_CNT = OFF_SSP + (size_t)NB * NCH * NI * NC * 4;  // int [NB][NCH][NI]
static const size_t OFF_KEY = OFF_CNT + (size_t)NB * NCH * NI * 4;       // u64 [NB][NCH][NI]
static const size_t WS_NEED = OFF_KEY + (size_t)NB * NCH * NI * 8;       // ~11.1 MB

__device__ __forceinline__ float4 ld4(const float* p) {
    return *reinterpret_cast<const float4*>(p);
}

// One MFMA k-step for this wave's 2 n-tiles: A-frag from mask words,
// B-frag packed from prefetched float4s (RNE v_cvt_pk_bf16_f32 via __bf16).
__device__ __forceinline__ void mfma_step(const uint16_t* __restrict__ lmp, int ks, int cl,
                                          const float4 (&buf)[2][2],
                                          f32x4& a0, f32x4& a1) {
    const uint4 wA = *reinterpret_cast<const uint4*>(lmp + ks * 32);
    u32x4 au;
    au.x = ((wA.x >> cl) & 0x10001u) * 0x3F80u;
    au.y = ((wA.y >> cl) & 0x10001u) * 0x3F80u;
    au.z = ((wA.z >> cl) & 0x10001u) * 0x3F80u;
    au.w = ((wA.w >> cl) & 0x10001u) * 0x3F80u;
    const bf16x8 av = __builtin_bit_cast(bf16x8, au);
    #pragma unroll
    for (int nt = 0; nt < 2; ++nt) {
        bf16x8 bv;
        bv[0] = (__bf16)buf[nt][0].x; bv[1] = (__bf16)buf[nt][0].y;
        bv[2] = (__bf16)buf[nt][0].z; bv[3] = (__bf16)buf[nt][0].w;
        bv[4] = (__bf16)buf[nt][1].x; bv[5] = (__bf16)buf[nt][1].y;
        bv[6] = (__bf16)buf[nt][1].z; bv[7] = (__bf16)buf[nt][1].w;
        f32x4& ac = (nt == 0) ? a0 : a1;
        ac = __builtin_amdgcn_mfma_f32_16x16x32_bf16(av, bv, ac, 0, 0, 0);
    }
}

// ---------------------------------------------------------------------------
// Fused per-chunk kernel. Block = 512 thr = 8 waves; owns one 256-pixel chunk
// of one (b, level).
// Phase A (instance-split + LOAD-BATCHED): tid<256 -> pixel tid, inst 0..7;
//   tid>=256 -> pixel tid-256, inst 8..15. ALL 8 instances' 2x2 scribble
//   samples are loaded into registers FIRST (one memory round-trip, ~16 loads
//   in flight), THEN the compare/ballot chain runs on registers -- the ballot
//   chain previously serialized 8 load round-trips. sr = exact 2x2 average
//   (bilinear, integer scale, half-pixel); threshold folded to s4 > 2.
//   u8 halves merged to u16 in LDS. cnt via ballot-popcount -> LDS atomic ->
//   chunk slot. Argmax key only when a whole wave sees zero foreground (dead
//   unless cnt==0 globally); key=(bits(sr)<<32)|(~pix).
// Phase B: ssum[i,c] = sum_p mask[i,p]*feat[c,p] via mfma_f32_16x16x32_bf16.
//   Wave w = channels w*32..w*32+31 (2 n-tiles); K = 256 chunk pixels =
//   8 k-steps, 2-buffer pipeline. A-frag: ((word>>i)&0x10001)*0x3F80 = two
//   bf16 {0,1}. C/D (m89): row=(lane>>4)*4+reg=instance, col=lane&15=channel.
//   Partial [16][256] -> private chunk slot (no atomics, no zeroing).
// ---------------------------------------------------------------------------
template<int W, int S, int P>
__device__ __forceinline__ void do_chunk(const float* __restrict__ f,
                                         const float* __restrict__ scr,
                                         float* __restrict__ ssp,
                                         int* __restrict__ cntp,
                                         unsigned long long* __restrict__ keyp,
                                         int b, int chunk, int slot, int tid,
                                         uint8_t* __restrict__ lmask8,
                                         uint16_t* __restrict__ lmask16,
                                         int* __restrict__ lcnt,
                                         unsigned long long* __restrict__ lkey) {
    // ---- phase-B addressing + early prefetch of ks=0 ----
    const int wave = tid >> 6;
    const int lane = tid & 63;
    const int kg = lane >> 4;   // k-subgroup 0..3
    const int cl = lane & 15;   // channel-within-tile (B/D) AND instance row (A)
    const int c0 = wave * 32;
    const int kb = chunk * 256;
    const float* fp0 = f + ((size_t)b * NC + c0 + cl) * P + kb + kg * 8;
    float4 bA[2][2], bB[2][2];
    #pragma unroll
    for (int nt = 0; nt < 2; ++nt) {
        const float* fr = fp0 + (size_t)(nt * 16) * P;
        bA[nt][0] = ld4(fr);
        bA[nt][1] = ld4(fr + 4);
    }

    // ---- phase A: batch-issue all scribble loads, then resolve ----
    const int gi = tid >> 8;        // instance group: 0 -> 0..7, 1 -> 8..15
    const int p = tid & 255;        // pixel within chunk
    const int pix = chunk * 256 + p;
    const int y = pix / W;
    const int x = pix - y * W;
    const int r0 = S * y + (S / 2 - 1);
    const int c0s = S * x + (S / 2 - 1);
    const float* sb = scr + ((size_t)b * NI + gi * 8) * (SH * SH) + (size_t)r0 * SH;
    float s4v[8];
    if constexpr (S == 4) {
        // c0s-1 = 4x -> 16B-aligned float4; cols 4x+1, 4x+2 are .y/.z
        float4 q0[8], q1[8];
        #pragma unroll
        for (int i = 0; i < 8; ++i) {
            const float* sp = sb + (size_t)i * (SH * SH);
            q0[i] = ld4(sp + (c0s - 1));
            q1[i] = ld4(sp + SH + (c0s - 1));
        }
        #pragma unroll
        for (int i = 0; i < 8; ++i)
            s4v[i] = (q0[i].y + q0[i].z) + (q1[i].y + q1[i].z);
    } else {
        float qa[8], qb[8], qc[8], qd[8];
        #pragma unroll
        for (int i = 0; i < 8; ++i) {
            const float* sp = sb + (size_t)i * (SH * SH);
            qa[i] = sp[c0s];
            qb[i] = sp[c0s + 1];
            qc[i] = sp[SH + c0s];
            qd[i] = sp[SH + c0s + 1];
        }
        #pragma unroll
        for (int i = 0; i < 8; ++i)
            s4v[i] = (qa[i] + qb[i]) + (qc[i] + qd[i]);
    }
    unsigned int mword = 0;
    #pragma unroll
    for (int i = 0; i < 8; ++i) {
        const float s4 = s4v[i];
        bool bit = s4 > 2.0f;                 // == (0.25*s4 > 0.5)
        mword |= bit ? (1u << i) : 0u;
        unsigned long long bal = __ballot(bit);
        if (lane == 0) atomicAdd(&lcnt[gi * 8 + i], (int)__popcll(bal));
        if (bal == 0ull) {                    // whole wave empty -> argmax path
            unsigned int srb = __float_as_uint(0.25f * s4);
            unsigned int mx = srb;
            #pragma unroll
            for (int off = 1; off < 64; off <<= 1) {
                unsigned int o = __shfl_xor(mx, off, 64);
                mx = (o > mx) ? o : mx;
            }
            unsigned long long win = __ballot(srb == mx);
            if (lane == 0) {
                int wl = __ffsll((unsigned long long)win) - 1;  // first = smallest pix
                unsigned int wpix = (unsigned int)(chunk * 256 + (p & ~63) + wl);
                unsigned long long key = (((unsigned long long)mx) << 32)
                                       | (unsigned long long)(0xFFFFFFFFu - wpix);
                atomicMax(&lkey[gi * 8 + i], key);
            }
        }
    }
    lmask8[gi * 256 + p] = (uint8_t)mword;
    __syncthreads();
    if (tid < 256)
        lmask16[tid] = (uint16_t)(lmask8[tid] | ((unsigned)lmask8[256 + tid] << 8));
    if (tid < NI) {
        cntp[slot * NI + tid] = lcnt[tid];
        keyp[slot * NI + tid] = lkey[tid];
    }
    __syncthreads();

    // ---- phase B: 2-buffer pipelined MFMA over 8 k-steps ----
    const uint16_t* lmp = lmask16 + kg * 8;
    f32x4 acc0 = {0.f, 0.f, 0.f, 0.f};
    f32x4 acc1 = {0.f, 0.f, 0.f, 0.f};
    #pragma unroll
    for (int ks = 0; ks < 8; ks += 2) {
        #pragma unroll
        for (int nt = 0; nt < 2; ++nt) {       // prefetch ks+1 -> bB
            const float* fr = fp0 + (size_t)(nt * 16) * P + (ks + 1) * 32;
            bB[nt][0] = ld4(fr);
            bB[nt][1] = ld4(fr + 4);
        }
        mfma_step(lmp, ks, cl, bA, acc0, acc1);
        if (ks + 2 < 8) {
            #pragma unroll
            for (int nt = 0; nt < 2; ++nt) {   // prefetch ks+2 -> bA
                const float* fr = fp0 + (size_t)(nt * 16) * P + (ks + 2) * 32;
                bA[nt][0] = ld4(fr);
                bA[nt][1] = ld4(fr + 4);
            }
        }
        mfma_step(lmp, ks + 1, cl, bB, acc0, acc1);
    }
    float* sb2 = ssp + (size_t)slot * (NI * NC);
    #pragma unroll
    for (int nt = 0; nt < 2; ++nt) {
        const f32x4 ac = (nt == 0) ? acc0 : acc1;
        const int c = c0 + nt * 16 + cl;
        #pragma unroll
        for (int r = 0; r < 4; ++r)
            sb2[(kg * 4 + r) * NC + c] = ac[r];
    }
}

__global__ __launch_bounds__(512, 4) void fused_kernel(const float* __restrict__ f0,
                                                       const float* __restrict__ f1,
                                                       const float* __restrict__ f2,
                                                       const float* __restrict__ scr,
                                                       float* __restrict__ ssp,
                                                       int* __restrict__ cntp,
                                                       unsigned long long* __restrict__ keyp) {
    __shared__ uint8_t lmask8[512];
    __shared__ __align__(16) uint16_t lmask16[256];
    __shared__ int lcnt[NI];
    __shared__ unsigned long long lkey[NI];
    const int tid = threadIdx.x;
    const int b = blockIdx.y;
    const int bx = blockIdx.x;
    if (tid < NI) { lcnt[tid] = 0; lkey[tid] = 0ull; }
    __syncthreads();
    const int slot = b * NCH + bx;
    if (bx < 64) {
        do_chunk<128, 4, 16384>(f0, scr, ssp, cntp, keyp, b, bx, slot, tid,
                                lmask8, lmask16, lcnt, lkey);
    } else if (bx < 80) {
        do_chunk<64, 8, 4096>(f1, scr, ssp, cntp, keyp, b, bx - 64, slot, tid,
                              lmask8, lmask16, lcnt, lkey);
    } else {
        do_chunk<32, 16, 1024>(f2, scr, ssp, cntp, keyp, b, bx - 80, slot, tid,
                               lmask8, lmask16, lcnt, lkey);
    }
}

// ---------------------------------------------------------------------------
// Finalize: grid (128, 4). Block = (b,i) x 64-channel quarter. 4 j-groups sum
// the per-chunk partials in parallel, LDS reduce; cnt/key reduced via LDS
// atomics. out = mean over levels of (cnt>0 ? ssum/cnt : feat[argmax]).
// ---------------------------------------------------------------------------
__global__ __launch_bounds__(256) void final_kernel(const float* __restrict__ f0,
                                                    const float* __restrict__ f1,
                                                    const float* __restrict__ f2,
                                                    const int* __restrict__ cntp,
                                                    const unsigned long long* __restrict__ keyp,
                                                    const float* __restrict__ ssp,
                                                    float* __restrict__ out) {
    __shared__ int scnt[3];
    __shared__ unsigned long long skey[3];
    __shared__ float red[4][64];
    const int bi = blockIdx.x;       // b*NI + i
    const int cq = blockIdx.y;       // channel quarter
    const int b = bi >> 4;
    const int i = bi & 15;
    const int tid = threadIdx.x;
    const int cl = tid & 63;
    const int jg = tid >> 6;
    const int CH[3] = {64, 16, 4};
    const int O[3] = {0, 64, 80};
    if (tid < 3) { scnt[tid] = 0; skey[tid] = 0ull; }
    __syncthreads();
    if (tid < NCH) {
        int l = (tid < 64) ? 0 : (tid < 80) ? 1 : 2;
        const int slot = b * NCH + tid;    // tid == O[l] + j already
        atomicAdd(&scnt[l], cntp[slot * NI + i]);
        atomicMax(&skey[l], keyp[slot * NI + i]);
    }
    __syncthreads();
    const float* fl[3] = {f0, f1, f2};
    const int Ps[3] = {16384, 4096, 1024};
    float r = 0.f;
    #pragma unroll
    for (int l = 0; l < 3; ++l) {
        const int cn = scnt[l];          // block-uniform
        if (cn > 0) {
            float s = 0.f;
            for (int j = jg; j < CH[l]; j += 4)
                s += ssp[((size_t)(b * NCH + O[l] + j) * NI + i) * NC + cq * 64 + cl];
            red[jg][cl] = s;
            __syncthreads();
            if (jg == 0)
                r += ((red[0][cl] + red[1][cl]) + (red[2][cl] + red[3][cl])) / (float)cn;
            __syncthreads();
        } else if (jg == 0) {
            unsigned int p = 0xFFFFFFFFu - (unsigned int)(skey[l] & 0xFFFFFFFFull);
            r += fl[l][((size_t)b * NC + cq * 64 + cl) * Ps[l] + p];
        }
    }
    if (jg == 0) out[(size_t)bi * NC + cq * 64 + cl] = r * (1.f / 3.f);
}

extern "C" void kernel_launch(void* const* d_in, const int* in_sizes, int n_in,
                              void* d_out, int out_size, void* d_ws, size_t ws_size,
                              hipStream_t stream) {
    const float* f0  = (const float*)d_in[0];   // [8,256,128,128]
    const float* f1  = (const float*)d_in[1];   // [8,256,64,64]
    const float* f2  = (const float*)d_in[2];   // [8,256,32,32]
    const float* scr = (const float*)d_in[3];   // [8,16,512,512]
    float* out = (float*)d_out;                 // [8,16,256]
    char* ws = (char*)d_ws;
    if (ws_size < WS_NEED) return;  // visible failure rather than corruption

    float* ssp = (float*)(ws + OFF_SSP);
    int* cntp = (int*)(ws + OFF_CNT);
    unsigned long long* keyp = (unsigned long long*)(ws + OFF_KEY);

    // no memset: every ws slot below is written unconditionally each call
    fused_kernel<<<dim3(NCH, NB), 512, 0, stream>>>(f0, f1, f2, scr, ssp, cntp, keyp);
    final_kernel<<<dim3(NB * NI, 4), 256, 0, stream>>>(f0, f1, f2, cntp, keyp, ssp, out);
}

// Round 9
// 64.069 us; speedup vs baseline: 1.0095x; 1.0095x over previous
//
#include <hip/hip_runtime.h>
#include <stdint.h>

#define NB 8
#define NI 16
#define NC 256
#define SH 512
#define NCH 84   // 256-pixel chunks per batch: 64 (L0) + 16 (L1) + 4 (L2)

typedef __bf16 bf16x8 __attribute__((ext_vector_type(8)));
typedef float f32x4 __attribute__((ext_vector_type(4)));
typedef uint32_t u32x4 __attribute__((ext_vector_type(4)));

// ws layout (bytes) — every slot written unconditionally every call: NO memset.
static const size_t OFF_SSP = 0;                                         // f32 [NB][NCH][NI][NC]
static const size_t OFF_CNT = OFF_SSP + (size_t)NB * NCH * NI * NC * 4;  // int [NB][NCH][NI]
static const size_t OFF_KEY = OFF_CNT + (size_t)NB * NCH * NI * 4;       // u64 [NB][NCH][NI]
static const size_t WS_NEED = OFF_KEY + (size_t)NB * NCH * NI * 8;       // ~11.1 MB

__device__ __forceinline__ float4 ld4(const float* p) {
    return *reinterpret_cast<const float4*>(p);
}

// One MFMA k-step for this wave's single 16-channel n-tile: A-frag from mask
// words, B-frag packed from prefetched float4s (RNE v_cvt_pk_bf16_f32).
__device__ __forceinline__ void mfma_step1(const uint16_t* __restrict__ lmp, int ks, int cl,
                                           const float4 (&buf)[2], f32x4& a0) {
    const uint4 wA = *reinterpret_cast<const uint4*>(lmp + ks * 32);
    u32x4 au;
    au.x = ((wA.x >> cl) & 0x10001u) * 0x3F80u;
    au.y = ((wA.y >> cl) & 0x10001u) * 0x3F80u;
    au.z = ((wA.z >> cl) & 0x10001u) * 0x3F80u;
    au.w = ((wA.w >> cl) & 0x10001u) * 0x3F80u;
    const bf16x8 av = __builtin_bit_cast(bf16x8, au);
    bf16x8 bv;
    bv[0] = (__bf16)buf[0].x; bv[1] = (__bf16)buf[0].y;
    bv[2] = (__bf16)buf[0].z; bv[3] = (__bf16)buf[0].w;
    bv[4] = (__bf16)buf[1].x; bv[5] = (__bf16)buf[1].y;
    bv[6] = (__bf16)buf[1].z; bv[7] = (__bf16)buf[1].w;
    a0 = __builtin_amdgcn_mfma_f32_16x16x32_bf16(av, bv, a0, 0, 0, 0);
}

// ---------------------------------------------------------------------------
// Fused per-chunk kernel. Block = 1024 thr = 16 waves; owns one 256-pixel
// chunk of one (b, level). 672 blocks x 16 waves = 10752 waves (131% of the
// 8192-wave device capacity) -> ~full occupancy at 2 blocks/CU (VGPR <= 64).
// Phase A (4-way instance split): quarter q = tid>>8 handles instances
//   q*4..q*4+3 for pixel tid&255. All 4 instances' 2x2 scribble samples are
//   batch-loaded, then the compare/ballot chain runs on registers. sr = exact
//   2x2 average (bilinear, integer scale, half-pixel); threshold folded to
//   s4 > 2. 4-bit nibbles merged to u16 in LDS. cnt via ballot-popcount ->
//   LDS atomic -> chunk slot. Argmax key only when a whole wave sees zero
//   foreground (dead unless cnt==0 globally); key=(bits(sr)<<32)|(~pix).
// Phase B: ssum[i,c] = sum_p mask[i,p]*feat[c,p] via mfma_f32_16x16x32_bf16.
//   Wave w = channels w*16..w*16+15 (one n-tile); K = 256 chunk pixels =
//   8 k-steps, 2-buffer prefetch. A-frag: ((word>>i)&0x10001)*0x3F80 = two
//   bf16 {0,1}. C/D (m89): row=(lane>>4)*4+reg=instance, col=lane&15=channel.
//   Partial [16][256] -> private chunk slot (no atomics, no zeroing).
// ---------------------------------------------------------------------------
template<int W, int S, int P>
__device__ __forceinline__ void do_chunk(const float* __restrict__ f,
                                         const float* __restrict__ scr,
                                         float* __restrict__ ssp,
                                         int* __restrict__ cntp,
                                         unsigned long long* __restrict__ keyp,
                                         int b, int chunk, int slot, int tid,
                                         uint8_t* __restrict__ lmask8,
                                         uint16_t* __restrict__ lmask16,
                                         int* __restrict__ lcnt,
                                         unsigned long long* __restrict__ lkey) {
    // ---- phase-B addressing + early prefetch of ks=0 ----
    const int wave = tid >> 6;
    const int lane = tid & 63;
    const int kg = lane >> 4;   // k-subgroup 0..3
    const int cl = lane & 15;   // channel-within-tile (B/D) AND instance row (A)
    const int c0 = wave * 16;   // one 16-channel n-tile per wave
    const int kb = chunk * 256;
    const float* fp0 = f + ((size_t)b * NC + c0 + cl) * P + kb + kg * 8;
    float4 bA[2], bB[2];
    bA[0] = ld4(fp0);
    bA[1] = ld4(fp0 + 4);

    // ---- phase A: batch-load 4 instances' samples, then resolve ----
    const int gi = tid >> 8;        // instance quarter: instances gi*4..gi*4+3
    const int p = tid & 255;        // pixel within chunk
    const int pix = chunk * 256 + p;
    const int y = pix / W;
    const int x = pix - y * W;
    const int r0 = S * y + (S / 2 - 1);
    const int c0s = S * x + (S / 2 - 1);
    const float* sb = scr + ((size_t)b * NI + gi * 4) * (SH * SH) + (size_t)r0 * SH;
    float s4v[4];
    if constexpr (S == 4) {
        // c0s-1 = 4x -> 16B-aligned float4; cols 4x+1, 4x+2 are .y/.z
        float4 q0[4], q1[4];
        #pragma unroll
        for (int i = 0; i < 4; ++i) {
            const float* sp = sb + (size_t)i * (SH * SH);
            q0[i] = ld4(sp + (c0s - 1));
            q1[i] = ld4(sp + SH + (c0s - 1));
        }
        #pragma unroll
        for (int i = 0; i < 4; ++i)
            s4v[i] = (q0[i].y + q0[i].z) + (q1[i].y + q1[i].z);
    } else {
        float qa[4], qb[4], qc[4], qd[4];
        #pragma unroll
        for (int i = 0; i < 4; ++i) {
            const float* sp = sb + (size_t)i * (SH * SH);
            qa[i] = sp[c0s];
            qb[i] = sp[c0s + 1];
            qc[i] = sp[SH + c0s];
            qd[i] = sp[SH + c0s + 1];
        }
        #pragma unroll
        for (int i = 0; i < 4; ++i)
            s4v[i] = (qa[i] + qb[i]) + (qc[i] + qd[i]);
    }
    unsigned int mword = 0;
    #pragma unroll
    for (int i = 0; i < 4; ++i) {
        const float s4 = s4v[i];
        bool bit = s4 > 2.0f;                 // == (0.25*s4 > 0.5)
        mword |= bit ? (1u << i) : 0u;
        unsigned long long bal = __ballot(bit);
        if (lane == 0) atomicAdd(&lcnt[gi * 4 + i], (int)__popcll(bal));
        if (bal == 0ull) {                    // whole wave empty -> argmax path
            unsigned int srb = __float_as_uint(0.25f * s4);
            unsigned int mx = srb;
            #pragma unroll
            for (int off = 1; off < 64; off <<= 1) {
                unsigned int o = __shfl_xor(mx, off, 64);
                mx = (o > mx) ? o : mx;
            }
            unsigned long long win = __ballot(srb == mx);
            if (lane == 0) {
                int wl = __ffsll((unsigned long long)win) - 1;  // first = smallest pix
                unsigned int wpix = (unsigned int)(chunk * 256 + (p & ~63) + wl);
                unsigned long long key = (((unsigned long long)mx) << 32)
                                       | (unsigned long long)(0xFFFFFFFFu - wpix);
                atomicMax(&lkey[gi * 4 + i], key);
            }
        }
    }
    lmask8[gi * 256 + p] = (uint8_t)mword;   // 4-bit nibble per quarter
    __syncthreads();
    if (tid < 256)
        lmask16[tid] = (uint16_t)((unsigned)lmask8[tid]
                                | ((unsigned)lmask8[256 + tid] << 4)
                                | ((unsigned)lmask8[512 + tid] << 8)
                                | ((unsigned)lmask8[768 + tid] << 12));
    if (tid < NI) {
        cntp[slot * NI + tid] = lcnt[tid];
        keyp[slot * NI + tid] = lkey[tid];
    }
    __syncthreads();

    // ---- phase B: 2-buffer pipelined MFMA over 8 k-steps ----
    const uint16_t* lmp = lmask16 + kg * 8;
    f32x4 acc = {0.f, 0.f, 0.f, 0.f};
    #pragma unroll
    for (int ks = 0; ks < 8; ks += 2) {
        {   // prefetch ks+1 -> bB
            const float* fr = fp0 + (ks + 1) * 32;
            bB[0] = ld4(fr);
            bB[1] = ld4(fr + 4);
        }
        mfma_step1(lmp, ks, cl, bA, acc);
        if (ks + 2 < 8) {   // prefetch ks+2 -> bA
            const float* fr = fp0 + (ks + 2) * 32;
            bA[0] = ld4(fr);
            bA[1] = ld4(fr + 4);
        }
        mfma_step1(lmp, ks + 1, cl, bB, acc);
    }
    float* sb2 = ssp + (size_t)slot * (NI * NC);
    const int c = c0 + cl;
    #pragma unroll
    for (int r = 0; r < 4; ++r)
        sb2[(kg * 4 + r) * NC + c] = acc[r];
}

__global__ __launch_bounds__(1024, 8) void fused_kernel(const float* __restrict__ f0,
                                                        const float* __restrict__ f1,
                                                        const float* __restrict__ f2,
                                                        const float* __restrict__ scr,
                                                        float* __restrict__ ssp,
                                                        int* __restrict__ cntp,
                                                        unsigned long long* __restrict__ keyp) {
    __shared__ uint8_t lmask8[1024];
    __shared__ __align__(16) uint16_t lmask16[256];
    __shared__ int lcnt[NI];
    __shared__ unsigned long long lkey[NI];
    const int tid = threadIdx.x;
    const int b = blockIdx.y;
    const int bx = blockIdx.x;
    if (tid < NI) { lcnt[tid] = 0; lkey[tid] = 0ull; }
    __syncthreads();
    const int slot = b * NCH + bx;
    if (bx < 64) {
        do_chunk<128, 4, 16384>(f0, scr, ssp, cntp, keyp, b, bx, slot, tid,
                                lmask8, lmask16, lcnt, lkey);
    } else if (bx < 80) {
        do_chunk<64, 8, 4096>(f1, scr, ssp, cntp, keyp, b, bx - 64, slot, tid,
                              lmask8, lmask16, lcnt, lkey);
    } else {
        do_chunk<32, 16, 1024>(f2, scr, ssp, cntp, keyp, b, bx - 80, slot, tid,
                               lmask8, lmask16, lcnt, lkey);
    }
}

// ---------------------------------------------------------------------------
// Finalize: grid (128, 4). Block = (b,i) x 64-channel quarter. 4 j-groups sum
// the per-chunk partials in parallel, LDS reduce; cnt/key reduced via LDS
// atomics. out = mean over levels of (cnt>0 ? ssum/cnt : feat[argmax]).
// ---------------------------------------------------------------------------
__global__ __launch_bounds__(256) void final_kernel(const float* __restrict__ f0,
                                                    const float* __restrict__ f1,
                                                    const float* __restrict__ f2,
                                                    const int* __restrict__ cntp,
                                                    const unsigned long long* __restrict__ keyp,
                                                    const float* __restrict__ ssp,
                                                    float* __restrict__ out) {
    __shared__ int scnt[3];
    __shared__ unsigned long long skey[3];
    __shared__ float red[4][64];
    const int bi = blockIdx.x;       // b*NI + i
    const int cq = blockIdx.y;       // channel quarter
    const int b = bi >> 4;
    const int i = bi & 15;
    const int tid = threadIdx.x;
    const int cl = tid & 63;
    const int jg = tid >> 6;
    const int CH[3] = {64, 16, 4};
    const int O[3] = {0, 64, 80};
    if (tid < 3) { scnt[tid] = 0; skey[tid] = 0ull; }
    __syncthreads();
    if (tid < NCH) {
        int l = (tid < 64) ? 0 : (tid < 80) ? 1 : 2;
        const int slot = b * NCH + tid;    // tid == O[l] + j already
        atomicAdd(&scnt[l], cntp[slot * NI + i]);
        atomicMax(&skey[l], keyp[slot * NI + i]);
    }
    __syncthreads();
    const float* fl[3] = {f0, f1, f2};
    const int Ps[3] = {16384, 4096, 1024};
    float r = 0.f;
    #pragma unroll
    for (int l = 0; l < 3; ++l) {
        const int cn = scnt[l];          // block-uniform
        if (cn > 0) {
            float s = 0.f;
            for (int j = jg; j < CH[l]; j += 4)
                s += ssp[((size_t)(b * NCH + O[l] + j) * NI + i) * NC + cq * 64 + cl];
            red[jg][cl] = s;
            __syncthreads();
            if (jg == 0)
                r += ((red[0][cl] + red[1][cl]) + (red[2][cl] + red[3][cl])) / (float)cn;
            __syncthreads();
        } else if (jg == 0) {
            unsigned int p = 0xFFFFFFFFu - (unsigned int)(skey[l] & 0xFFFFFFFFull);
            r += fl[l][((size_t)b * NC + cq * 64 + cl) * Ps[l] + p];
        }
    }
    if (jg == 0) out[(size_t)bi * NC + cq * 64 + cl] = r * (1.f / 3.f);
}

extern "C" void kernel_launch(void* const* d_in, const int* in_sizes, int n_in,
                              void* d_out, int out_size, void* d_ws, size_t ws_size,
                              hipStream_t stream) {
    const float* f0  = (const float*)d_in[0];   // [8,256,128,128]
    const float* f1  = (const float*)d_in[1];   // [8,256,64,64]
    const float* f2  = (const float*)d_in[2];   // [8,256,32,32]
    const float* scr = (const float*)d_in[3];   // [8,16,512,512]
    float* out = (float*)d_out;                 // [8,16,256]
    char* ws = (char*)d_ws;
    if (ws_size < WS_NEED) return;  // visible failure rather than corruption

    float* ssp = (float*)(ws + OFF_SSP);
    int* cntp = (int*)(ws + OFF_CNT);
    unsigned long long* keyp = (unsigned long long*)(ws + OFF_KEY);

    // no memset: every ws slot below is written unconditionally each call
    fused_kernel<<<dim3(NCH, NB), 1024, 0, stream>>>(f0, f1, f2, scr, ssp, cntp, keyp);
    final_kernel<<<dim3(NB * NI, 4), 256, 0, stream>>>(f0, f1, f2, cntp, keyp, ssp, out);
}

// Round 10
// 61.719 us; speedup vs baseline: 1.0480x; 1.0381x over previous
//
#include <hip/hip_runtime.h>
#include <stdint.h>

#define NB 8
#define NI 16
#define NC 256
#define SH 512
#define NCH 84   // 256-pixel chunks per batch: 64 (L0) + 16 (L1) + 4 (L2)

typedef __bf16 bf16x8 __attribute__((ext_vector_type(8)));
typedef float f32x4 __attribute__((ext_vector_type(4)));
typedef uint32_t u32x4 __attribute__((ext_vector_type(4)));

// ws layout (bytes): small L2-resident accumulators, zeroed by zero_kernel
// each call (zero -> fused -> final in one stream = safe ordering).
static const size_t OFF_SSUM = 0;                                        // f32 [3][NB][NI][NC] = 393216 B
static const size_t OFF_CNT  = OFF_SSUM + (size_t)3 * NB * NI * NC * 4;  // int [3][NB][NI]    = 1536 B
static const size_t OFF_KEY  = OFF_CNT + (size_t)3 * NB * NI * 4;        // u64 [3][NB][NI]    = 3072 B
static const size_t WS_NEED  = OFF_KEY + (size_t)3 * NB * NI * 8;        // ~398 KB
static const int    ZERO_N4  = (int)(WS_NEED / 16);                      // float4 count (16-div)

__device__ __forceinline__ float4 ld4(const float* p) {
    return *reinterpret_cast<const float4*>(p);
}

// Zero the accumulator region (float4 stores; WS_NEED is 16B-divisible).
__global__ __launch_bounds__(256) void zero_kernel(float4* __restrict__ ws4) {
    const int i = blockIdx.x * 256 + threadIdx.x;
    if (i < ZERO_N4) ws4[i] = make_float4(0.f, 0.f, 0.f, 0.f);
}

// One MFMA k-step for this wave's single 16-channel n-tile: A-frag from mask
// words, B-frag packed from prefetched float4s (RNE v_cvt_pk_bf16_f32).
__device__ __forceinline__ void mfma_step1(const uint16_t* __restrict__ lmp, int ks, int cl,
                                           const float4 (&buf)[2], f32x4& a0) {
    const uint4 wA = *reinterpret_cast<const uint4*>(lmp + ks * 32);
    u32x4 au;
    au.x = ((wA.x >> cl) & 0x10001u) * 0x3F80u;
    au.y = ((wA.y >> cl) & 0x10001u) * 0x3F80u;
    au.z = ((wA.z >> cl) & 0x10001u) * 0x3F80u;
    au.w = ((wA.w >> cl) & 0x10001u) * 0x3F80u;
    const bf16x8 av = __builtin_bit_cast(bf16x8, au);
    bf16x8 bv;
    bv[0] = (__bf16)buf[0].x; bv[1] = (__bf16)buf[0].y;
    bv[2] = (__bf16)buf[0].z; bv[3] = (__bf16)buf[0].w;
    bv[4] = (__bf16)buf[1].x; bv[5] = (__bf16)buf[1].y;
    bv[6] = (__bf16)buf[1].z; bv[7] = (__bf16)buf[1].w;
    a0 = __builtin_amdgcn_mfma_f32_16x16x32_bf16(av, bv, a0, 0, 0, 0);
}

// ---------------------------------------------------------------------------
// Fused per-chunk kernel. Block = 1024 thr = 16 waves; owns one 256-pixel
// chunk of one (b, level). 672 blocks x 16 waves -> ~2 blocks/CU.
// Phase A (4-way instance split): quarter q = tid>>8 handles instances
//   q*4..q*4+3 for pixel tid&255; batch-loaded 2x2 scribble samples, then
//   compare/ballot on registers. sr = exact 2x2 average (bilinear at integer
//   scale, half-pixel centers); threshold folded to s4 > 2. Nibbles merged
//   to u16 masks in LDS. cnt: ballot-popcount -> LDS -> ONE global atomicAdd
//   per (block, i) (integer = deterministic). Argmax key only when a whole
//   wave sees zero foreground (dead unless cnt==0 globally); global atomicMax
//   skipped when key==0 (common case). key=(bits(sr)<<32)|(~pix).
// Phase B: ssum[i,c] += sum_p mask[i,p]*feat[c,p] via mfma_f32_16x16x32_bf16.
//   Wave w = channels w*16..w*16+15; K = 256 chunk pixels = 8 k-steps,
//   2-buffer prefetch. C/D (m89): row=(lane>>4)*4+reg=instance,
//   col=lane&15=channel. Tile accumulated into the small L2-resident global
//   accumulator via atomicAdd (4096 distinct addresses per block; fp-order
//   nondeterminism is ~1 ulp, far under validation threshold).
// ---------------------------------------------------------------------------
template<int W, int S, int P>
__device__ __forceinline__ void do_chunk(const float* __restrict__ f,
                                         const float* __restrict__ scr,
                                         float* __restrict__ ssum_lb,   // + (l*NB+b)*NI*NC
                                         int* __restrict__ cnt_lb,     // + (l*NB+b)*NI
                                         unsigned long long* __restrict__ key_lb,
                                         int b, int chunk, int tid,
                                         uint8_t* __restrict__ lmask8,
                                         uint16_t* __restrict__ lmask16,
                                         int* __restrict__ lcnt,
                                         unsigned long long* __restrict__ lkey) {
    // ---- phase-B addressing + early prefetch of ks=0 ----
    const int wave = tid >> 6;
    const int lane = tid & 63;
    const int kg = lane >> 4;   // k-subgroup 0..3
    const int cl = lane & 15;   // channel-within-tile (B/D) AND instance row (A)
    const int c0 = wave * 16;   // one 16-channel n-tile per wave
    const int kb = chunk * 256;
    const float* fp0 = f + ((size_t)b * NC + c0 + cl) * P + kb + kg * 8;
    float4 bA[2], bB[2];
    bA[0] = ld4(fp0);
    bA[1] = ld4(fp0 + 4);

    // ---- phase A: batch-load 4 instances' samples, then resolve ----
    const int gi = tid >> 8;        // instance quarter: instances gi*4..gi*4+3
    const int p = tid & 255;        // pixel within chunk
    const int pix = chunk * 256 + p;
    const int y = pix / W;
    const int x = pix - y * W;
    const int r0 = S * y + (S / 2 - 1);
    const int c0s = S * x + (S / 2 - 1);
    const float* sb = scr + ((size_t)b * NI + gi * 4) * (SH * SH) + (size_t)r0 * SH;
    float s4v[4];
    if constexpr (S == 4) {
        // c0s-1 = 4x -> 16B-aligned float4; cols 4x+1, 4x+2 are .y/.z
        float4 q0[4], q1[4];
        #pragma unroll
        for (int i = 0; i < 4; ++i) {
            const float* sp = sb + (size_t)i * (SH * SH);
            q0[i] = ld4(sp + (c0s - 1));
            q1[i] = ld4(sp + SH + (c0s - 1));
        }
        #pragma unroll
        for (int i = 0; i < 4; ++i)
            s4v[i] = (q0[i].y + q0[i].z) + (q1[i].y + q1[i].z);
    } else {
        float qa[4], qb[4], qc[4], qd[4];
        #pragma unroll
        for (int i = 0; i < 4; ++i) {
            const float* sp = sb + (size_t)i * (SH * SH);
            qa[i] = sp[c0s];
            qb[i] = sp[c0s + 1];
            qc[i] = sp[SH + c0s];
            qd[i] = sp[SH + c0s + 1];
        }
        #pragma unroll
        for (int i = 0; i < 4; ++i)
            s4v[i] = (qa[i] + qb[i]) + (qc[i] + qd[i]);
    }
    unsigned int mword = 0;
    #pragma unroll
    for (int i = 0; i < 4; ++i) {
        const float s4 = s4v[i];
        bool bit = s4 > 2.0f;                 // == (0.25*s4 > 0.5)
        mword |= bit ? (1u << i) : 0u;
        unsigned long long bal = __ballot(bit);
        if (lane == 0) atomicAdd(&lcnt[gi * 4 + i], (int)__popcll(bal));
        if (bal == 0ull) {                    // whole wave empty -> argmax path
            unsigned int srb = __float_as_uint(0.25f * s4);
            unsigned int mx = srb;
            #pragma unroll
            for (int off = 1; off < 64; off <<= 1) {
                unsigned int o = __shfl_xor(mx, off, 64);
                mx = (o > mx) ? o : mx;
            }
            unsigned long long win = __ballot(srb == mx);
            if (lane == 0) {
                int wl = __ffsll((unsigned long long)win) - 1;  // first = smallest pix
                unsigned int wpix = (unsigned int)(chunk * 256 + (p & ~63) + wl);
                unsigned long long key = (((unsigned long long)mx) << 32)
                                       | (unsigned long long)(0xFFFFFFFFu - wpix);
                atomicMax(&lkey[gi * 4 + i], key);
            }
        }
    }
    lmask8[gi * 256 + p] = (uint8_t)mword;   // 4-bit nibble per quarter
    __syncthreads();
    if (tid < 256)
        lmask16[tid] = (uint16_t)((unsigned)lmask8[tid]
                                | ((unsigned)lmask8[256 + tid] << 4)
                                | ((unsigned)lmask8[512 + tid] << 8)
                                | ((unsigned)lmask8[768 + tid] << 12));
    if (tid < NI) {
        int v = lcnt[tid];
        if (v) atomicAdd(&cnt_lb[tid], v);                 // int add: deterministic
        unsigned long long k = lkey[tid];
        if (k) atomicMax(&key_lb[tid], k);                 // rare path only
    }
    __syncthreads();

    // ---- phase B: 2-buffer pipelined MFMA over 8 k-steps ----
    const uint16_t* lmp = lmask16 + kg * 8;
    f32x4 acc = {0.f, 0.f, 0.f, 0.f};
    #pragma unroll
    for (int ks = 0; ks < 8; ks += 2) {
        {   // prefetch ks+1 -> bB
            const float* fr = fp0 + (ks + 1) * 32;
            bB[0] = ld4(fr);
            bB[1] = ld4(fr + 4);
        }
        mfma_step1(lmp, ks, cl, bA, acc);
        if (ks + 2 < 8) {   // prefetch ks+2 -> bA
            const float* fr = fp0 + (ks + 2) * 32;
            bA[0] = ld4(fr);
            bA[1] = ld4(fr + 4);
        }
        mfma_step1(lmp, ks + 1, cl, bB, acc);
    }
    const int c = c0 + cl;
    #pragma unroll
    for (int r = 0; r < 4; ++r)
        atomicAdd(&ssum_lb[(kg * 4 + r) * NC + c], acc[r]);
}

__global__ __launch_bounds__(1024, 8) void fused_kernel(const float* __restrict__ f0,
                                                        const float* __restrict__ f1,
                                                        const float* __restrict__ f2,
                                                        const float* __restrict__ scr,
                                                        float* __restrict__ ssum,
                                                        int* __restrict__ cnt,
                                                        unsigned long long* __restrict__ key) {
    __shared__ uint8_t lmask8[1024];
    __shared__ __align__(16) uint16_t lmask16[256];
    __shared__ int lcnt[NI];
    __shared__ unsigned long long lkey[NI];
    const int tid = threadIdx.x;
    const int b = blockIdx.y;
    const int bx = blockIdx.x;
    if (tid < NI) { lcnt[tid] = 0; lkey[tid] = 0ull; }
    __syncthreads();
    if (bx < 64) {
        const size_t o = (size_t)(0 * NB + b);
        do_chunk<128, 4, 16384>(f0, scr, ssum + o * NI * NC, cnt + o * NI, key + o * NI,
                                b, bx, tid, lmask8, lmask16, lcnt, lkey);
    } else if (bx < 80) {
        const size_t o = (size_t)(1 * NB + b);
        do_chunk<64, 8, 4096>(f1, scr, ssum + o * NI * NC, cnt + o * NI, key + o * NI,
                              b, bx - 64, tid, lmask8, lmask16, lcnt, lkey);
    } else {
        const size_t o = (size_t)(2 * NB + b);
        do_chunk<32, 16, 1024>(f2, scr, ssum + o * NI * NC, cnt + o * NI, key + o * NI,
                               b, bx - 80, tid, lmask8, lmask16, lcnt, lkey);
    }
}

// ---------------------------------------------------------------------------
// Finalize (lite): 128 blocks x 256 thr; block = (b,i), thread = channel.
// out = mean over levels of (cnt>0 ? ssum/cnt : feat[argmax]).
// ---------------------------------------------------------------------------
__global__ __launch_bounds__(256) void final_kernel(const float* __restrict__ f0,
                                                    const float* __restrict__ f1,
                                                    const float* __restrict__ f2,
                                                    const int* __restrict__ cnt,
                                                    const unsigned long long* __restrict__ key,
                                                    const float* __restrict__ ssum,
                                                    float* __restrict__ out) {
    const int bi = blockIdx.x;       // b*NI + i
    const int c = threadIdx.x;
    const int b = bi >> 4;
    const float* fl[3] = {f0, f1, f2};
    const int Ps[3] = {16384, 4096, 1024};
    float r = 0.f;
    #pragma unroll
    for (int l = 0; l < 3; ++l) {
        const int cn = cnt[l * NB * NI + bi];
        float v;
        if (cn > 0) {
            v = ssum[((size_t)l * NB * NI + bi) * NC + c] / (float)cn;
        } else {
            unsigned int p = 0xFFFFFFFFu -
                (unsigned int)(key[l * NB * NI + bi] & 0xFFFFFFFFull);
            v = fl[l][((size_t)b * NC + c) * Ps[l] + p];
        }
        r += v;
    }
    out[(size_t)bi * NC + c] = r * (1.f / 3.f);
}

extern "C" void kernel_launch(void* const* d_in, const int* in_sizes, int n_in,
                              void* d_out, int out_size, void* d_ws, size_t ws_size,
                              hipStream_t stream) {
    const float* f0  = (const float*)d_in[0];   // [8,256,128,128]
    const float* f1  = (const float*)d_in[1];   // [8,256,64,64]
    const float* f2  = (const float*)d_in[2];   // [8,256,32,32]
    const float* scr = (const float*)d_in[3];   // [8,16,512,512]
    float* out = (float*)d_out;                 // [8,16,256]
    char* ws = (char*)d_ws;
    if (ws_size < WS_NEED) return;  // visible failure rather than corruption

    float* ssum = (float*)(ws + OFF_SSUM);
    int* cnt = (int*)(ws + OFF_CNT);
    unsigned long long* key = (unsigned long long*)(ws + OFF_KEY);

    zero_kernel<<<(ZERO_N4 + 255) / 256, 256, 0, stream>>>((float4*)ws);
    fused_kernel<<<dim3(NCH, NB), 1024, 0, stream>>>(f0, f1, f2, scr, ssum, cnt, key);
    final_kernel<<<NB * NI, NC, 0, stream>>>(f0, f1, f2, cnt, key, ssum, out);
}

// Round 11
// 61.577 us; speedup vs baseline: 1.0504x; 1.0023x over previous
//
#include <hip/hip_runtime.h>
#include <stdint.h>

#define NB 8
#define NI 16
#define NC 256
#define SH 512
#define NCH 84   // 256-pixel chunks per batch: 64 (L0) + 16 (L1) + 4 (L2)

typedef __bf16 bf16x8 __attribute__((ext_vector_type(8)));
typedef float f32x4 __attribute__((ext_vector_type(4)));
typedef uint32_t u32x4 __attribute__((ext_vector_type(4)));

// ws layout (bytes): small L2-resident accumulators, zeroed by zero_kernel
// each call (zero -> fused -> final in one stream = safe ordering).
static const size_t OFF_SSUM = 0;                                        // f32 [3][NB][NI][NC] = 393216 B
static const size_t OFF_CNT  = OFF_SSUM + (size_t)3 * NB * NI * NC * 4;  // int [3][NB][NI]    = 1536 B
static const size_t OFF_KEY  = OFF_CNT + (size_t)3 * NB * NI * 4;        // u64 [3][NB][NI]    = 3072 B
static const size_t WS_NEED  = OFF_KEY + (size_t)3 * NB * NI * 8;        // ~398 KB
static const int    ZERO_N4  = (int)(WS_NEED / 16);                      // float4 count (16-div)

__device__ __forceinline__ float4 ld4(const float* p) {
    return *reinterpret_cast<const float4*>(p);
}

// Zero the accumulator region (float4 stores; WS_NEED is 16B-divisible).
__global__ __launch_bounds__(256) void zero_kernel(float4* __restrict__ ws4) {
    const int i = blockIdx.x * 256 + threadIdx.x;
    if (i < ZERO_N4) ws4[i] = make_float4(0.f, 0.f, 0.f, 0.f);
}

// One MFMA k-step for this wave's single 16-channel n-tile: A-frag from mask
// words, B-frag packed from prefetched float4s (RNE v_cvt_pk_bf16_f32).
__device__ __forceinline__ void mfma_step1(const uint16_t* __restrict__ lmp, int ks, int cl,
                                           const float4 (&buf)[2], f32x4& a0) {
    const uint4 wA = *reinterpret_cast<const uint4*>(lmp + ks * 32);
    u32x4 au;
    au.x = ((wA.x >> cl) & 0x10001u) * 0x3F80u;
    au.y = ((wA.y >> cl) & 0x10001u) * 0x3F80u;
    au.z = ((wA.z >> cl) & 0x10001u) * 0x3F80u;
    au.w = ((wA.w >> cl) & 0x10001u) * 0x3F80u;
    const bf16x8 av = __builtin_bit_cast(bf16x8, au);
    bf16x8 bv;
    bv[0] = (__bf16)buf[0].x; bv[1] = (__bf16)buf[0].y;
    bv[2] = (__bf16)buf[0].z; bv[3] = (__bf16)buf[0].w;
    bv[4] = (__bf16)buf[1].x; bv[5] = (__bf16)buf[1].y;
    bv[6] = (__bf16)buf[1].z; bv[7] = (__bf16)buf[1].w;
    a0 = __builtin_amdgcn_mfma_f32_16x16x32_bf16(av, bv, a0, 0, 0, 0);
}

// ---------------------------------------------------------------------------
// Fused per-chunk kernel. Block = 1024 thr = 16 waves; owns one 256-pixel
// chunk of one (b, level). 672 blocks x 16 waves -> ~2 blocks/CU.
// Pipeline shape (per wave): issue feature ks=0,1 (4 ld4) -> issue all 8
//   scribble ld4 (phase A) -> resolve masks (1 combined HBM round trip) ->
//   issue ks=2,3 -> 8-step MFMA loop prefetching ks+4 each step (4-deep,
//   ~8 loads in flight steady-state; was 2-deep).
// Phase A (4-way instance split): quarter q = tid>>8 handles instances
//   q*4..q*4+3 for pixel tid&255; batch-loaded 2x2 scribble samples, then
//   compare/ballot on registers. sr = exact 2x2 average (bilinear at integer
//   scale, half-pixel centers); threshold folded to s4 > 2. Nibbles merged
//   to u16 masks in LDS. cnt: ballot-popcount -> LDS -> ONE global atomicAdd
//   per (block, i) (integer = deterministic). Argmax key only when a whole
//   wave sees zero foreground (dead unless cnt==0 globally); global atomicMax
//   skipped when key==0 (common case). key=(bits(sr)<<32)|(~pix).
// Phase B: ssum[i,c] += sum_p mask[i,p]*feat[c,p] via mfma_f32_16x16x32_bf16.
//   Wave w = channels w*16..w*16+15; K = 256 chunk pixels = 8 k-steps.
//   C/D (m89): row=(lane>>4)*4+reg=instance, col=lane&15=channel. Tile
//   accumulated into the small L2-resident global accumulator via atomicAdd
//   (4096 distinct addresses per block; fp-order nondeterminism ~1 ulp).
// ---------------------------------------------------------------------------
template<int W, int S, int P>
__device__ __forceinline__ void do_chunk(const float* __restrict__ f,
                                         const float* __restrict__ scr,
                                         float* __restrict__ ssum_lb,   // + (l*NB+b)*NI*NC
                                         int* __restrict__ cnt_lb,     // + (l*NB+b)*NI
                                         unsigned long long* __restrict__ key_lb,
                                         int b, int chunk, int tid,
                                         uint8_t* __restrict__ lmask8,
                                         uint16_t* __restrict__ lmask16,
                                         int* __restrict__ lcnt,
                                         unsigned long long* __restrict__ lkey) {
    // ---- phase-B addressing + early prefetch of ks=0,1 ----
    const int wave = tid >> 6;
    const int lane = tid & 63;
    const int kg = lane >> 4;   // k-subgroup 0..3
    const int cl = lane & 15;   // channel-within-tile (B/D) AND instance row (A)
    const int c0 = wave * 16;   // one 16-channel n-tile per wave
    const int kb = chunk * 256;
    const float* fp0 = f + ((size_t)b * NC + c0 + cl) * P + kb + kg * 8;
    float4 buf[4][2];
    #pragma unroll
    for (int k = 0; k < 2; ++k) {
        buf[k][0] = ld4(fp0 + k * 32);
        buf[k][1] = ld4(fp0 + k * 32 + 4);
    }

    // ---- phase A: batch-load 4 instances' samples, then resolve ----
    const int gi = tid >> 8;        // instance quarter: instances gi*4..gi*4+3
    const int p = tid & 255;        // pixel within chunk
    const int pix = chunk * 256 + p;
    const int y = pix / W;
    const int x = pix - y * W;
    const int r0 = S * y + (S / 2 - 1);
    const int c0s = S * x + (S / 2 - 1);
    const float* sb = scr + ((size_t)b * NI + gi * 4) * (SH * SH) + (size_t)r0 * SH;
    float s4v[4];
    if constexpr (S == 4) {
        // c0s-1 = 4x -> 16B-aligned float4; cols 4x+1, 4x+2 are .y/.z
        float4 q0[4], q1[4];
        #pragma unroll
        for (int i = 0; i < 4; ++i) {
            const float* sp = sb + (size_t)i * (SH * SH);
            q0[i] = ld4(sp + (c0s - 1));
            q1[i] = ld4(sp + SH + (c0s - 1));
        }
        #pragma unroll
        for (int i = 0; i < 4; ++i)
            s4v[i] = (q0[i].y + q0[i].z) + (q1[i].y + q1[i].z);
    } else {
        float qa[4], qb[4], qc[4], qd[4];
        #pragma unroll
        for (int i = 0; i < 4; ++i) {
            const float* sp = sb + (size_t)i * (SH * SH);
            qa[i] = sp[c0s];
            qb[i] = sp[c0s + 1];
            qc[i] = sp[SH + c0s];
            qd[i] = sp[SH + c0s + 1];
        }
        #pragma unroll
        for (int i = 0; i < 4; ++i)
            s4v[i] = (qa[i] + qb[i]) + (qc[i] + qd[i]);
    }
    unsigned int mword = 0;
    #pragma unroll
    for (int i = 0; i < 4; ++i) {
        const float s4 = s4v[i];
        bool bit = s4 > 2.0f;                 // == (0.25*s4 > 0.5)
        mword |= bit ? (1u << i) : 0u;
        unsigned long long bal = __ballot(bit);
        if (lane == 0) atomicAdd(&lcnt[gi * 4 + i], (int)__popcll(bal));
        if (bal == 0ull) {                    // whole wave empty -> argmax path
            unsigned int srb = __float_as_uint(0.25f * s4);
            unsigned int mx = srb;
            #pragma unroll
            for (int off = 1; off < 64; off <<= 1) {
                unsigned int o = __shfl_xor(mx, off, 64);
                mx = (o > mx) ? o : mx;
            }
            unsigned long long win = __ballot(srb == mx);
            if (lane == 0) {
                int wl = __ffsll((unsigned long long)win) - 1;  // first = smallest pix
                unsigned int wpix = (unsigned int)(chunk * 256 + (p & ~63) + wl);
                unsigned long long key = (((unsigned long long)mx) << 32)
                                       | (unsigned long long)(0xFFFFFFFFu - wpix);
                atomicMax(&lkey[gi * 4 + i], key);
            }
        }
    }
    lmask8[gi * 256 + p] = (uint8_t)mword;   // 4-bit nibble per quarter
    __syncthreads();
    if (tid < 256)
        lmask16[tid] = (uint16_t)((unsigned)lmask8[tid]
                                | ((unsigned)lmask8[256 + tid] << 4)
                                | ((unsigned)lmask8[512 + tid] << 8)
                                | ((unsigned)lmask8[768 + tid] << 12));
    __syncthreads();

    // ---- phase B: 4-deep pipelined MFMA over 8 k-steps ----
    #pragma unroll
    for (int k = 2; k < 4; ++k) {           // complete the 4-deep prologue
        buf[k][0] = ld4(fp0 + k * 32);
        buf[k][1] = ld4(fp0 + k * 32 + 4);
    }
    const uint16_t* lmp = lmask16 + kg * 8;
    f32x4 acc = {0.f, 0.f, 0.f, 0.f};
    #pragma unroll
    for (int ks = 0; ks < 8; ++ks) {
        mfma_step1(lmp, ks, cl, buf[ks & 3], acc);
        if (ks + 4 < 8) {                    // refill the slot just consumed
            buf[ks & 3][0] = ld4(fp0 + (ks + 4) * 32);
            buf[ks & 3][1] = ld4(fp0 + (ks + 4) * 32 + 4);
        }
    }
    const int c = c0 + cl;
    #pragma unroll
    for (int r = 0; r < 4; ++r)
        atomicAdd(&ssum_lb[(kg * 4 + r) * NC + c], acc[r]);

    // ---- flush per-block cnt/key (off the MFMA critical path) ----
    if (tid < NI) {
        int v = lcnt[tid];
        if (v) atomicAdd(&cnt_lb[tid], v);                 // int add: deterministic
        unsigned long long k = lkey[tid];
        if (k) atomicMax(&key_lb[tid], k);                 // rare path only
    }
}

__global__ __launch_bounds__(1024, 8) void fused_kernel(const float* __restrict__ f0,
                                                        const float* __restrict__ f1,
                                                        const float* __restrict__ f2,
                                                        const float* __restrict__ scr,
                                                        float* __restrict__ ssum,
                                                        int* __restrict__ cnt,
                                                        unsigned long long* __restrict__ key) {
    __shared__ uint8_t lmask8[1024];
    __shared__ __align__(16) uint16_t lmask16[256];
    __shared__ int lcnt[NI];
    __shared__ unsigned long long lkey[NI];
    const int tid = threadIdx.x;
    const int b = blockIdx.y;
    const int bx = blockIdx.x;
    if (tid < NI) { lcnt[tid] = 0; lkey[tid] = 0ull; }
    __syncthreads();
    if (bx < 64) {
        const size_t o = (size_t)(0 * NB + b);
        do_chunk<128, 4, 16384>(f0, scr, ssum + o * NI * NC, cnt + o * NI, key + o * NI,
                                b, bx, tid, lmask8, lmask16, lcnt, lkey);
    } else if (bx < 80) {
        const size_t o = (size_t)(1 * NB + b);
        do_chunk<64, 8, 4096>(f1, scr, ssum + o * NI * NC, cnt + o * NI, key + o * NI,
                              b, bx - 64, tid, lmask8, lmask16, lcnt, lkey);
    } else {
        const size_t o = (size_t)(2 * NB + b);
        do_chunk<32, 16, 1024>(f2, scr, ssum + o * NI * NC, cnt + o * NI, key + o * NI,
                               b, bx - 80, tid, lmask8, lmask16, lcnt, lkey);
    }
}

// ---------------------------------------------------------------------------
// Finalize (lite): 128 blocks x 256 thr; block = (b,i), thread = channel.
// out = mean over levels of (cnt>0 ? ssum/cnt : feat[argmax]).
// ---------------------------------------------------------------------------
__global__ __launch_bounds__(256) void final_kernel(const float* __restrict__ f0,
                                                    const float* __restrict__ f1,
                                                    const float* __restrict__ f2,
                                                    const int* __restrict__ cnt,
                                                    const unsigned long long* __restrict__ key,
                                                    const float* __restrict__ ssum,
                                                    float* __restrict__ out) {
    const int bi = blockIdx.x;       // b*NI + i
    const int c = threadIdx.x;
    const int b = bi >> 4;
    const float* fl[3] = {f0, f1, f2};
    const int Ps[3] = {16384, 4096, 1024};
    float r = 0.f;
    #pragma unroll
    for (int l = 0; l < 3; ++l) {
        const int cn = cnt[l * NB * NI + bi];
        float v;
        if (cn > 0) {
            v = ssum[((size_t)l * NB * NI + bi) * NC + c] / (float)cn;
        } else {
            unsigned int p = 0xFFFFFFFFu -
                (unsigned int)(key[l * NB * NI + bi] & 0xFFFFFFFFull);
            v = fl[l][((size_t)b * NC + c) * Ps[l] + p];
        }
        r += v;
    }
    out[(size_t)bi * NC + c] = r * (1.f / 3.f);
}

extern "C" void kernel_launch(void* const* d_in, const int* in_sizes, int n_in,
                              void* d_out, int out_size, void* d_ws, size_t ws_size,
                              hipStream_t stream) {
    const float* f0  = (const float*)d_in[0];   // [8,256,128,128]
    const float* f1  = (const float*)d_in[1];   // [8,256,64,64]
    const float* f2  = (const float*)d_in[2];   // [8,256,32,32]
    const float* scr = (const float*)d_in[3];   // [8,16,512,512]
    float* out = (float*)d_out;                 // [8,16,256]
    char* ws = (char*)d_ws;
    if (ws_size < WS_NEED) return;  // visible failure rather than corruption

    float* ssum = (float*)(ws + OFF_SSUM);
    int* cnt = (int*)(ws + OFF_CNT);
    unsigned long long* key = (unsigned long long*)(ws + OFF_KEY);

    zero_kernel<<<(ZERO_N4 + 255) / 256, 256, 0, stream>>>((float4*)ws);
    fused_kernel<<<dim3(NCH, NB), 1024, 0, stream>>>(f0, f1, f2, scr, ssum, cnt, key);
    final_kernel<<<NB * NI, NC, 0, stream>>>(f0, f1, f2, cnt, key, ssum, out);
}